// Round 7
// baseline (1460.882 us; speedup 1.0000x reference)
//
#include <hip/hip_runtime.h>
#include <cstddef>

constexpr int N0 = 16384, N1 = 4096, N2 = 1024, N3 = 256;
constexpr int E0 = 6 * N0, E1 = 6 * N1, E2 = 6 * N2, E3 = 6 * N3;
constexpr int ETOT = E0 + E1 + E2 + E3; // 129024
constexpr int LOCN = 32 * N0;           // 524288
constexpr int NB = 256;                 // 1 block per CU (proven resident)
constexpr int NT = 1024;                // 16 waves/block -> 4 waves/SIMD

// ---- workspace layout (float offsets) ----
constexpr size_t O_XLZ  = 0;
constexpr size_t O_STAT = 128;
constexpr size_t O_XW0  = 512;
constexpr size_t O_YG0  = 2560;
constexpr size_t O_XG1  = 10752;
constexpr size_t O_XWG1 = 18944;
constexpr size_t O_YG1  = 27136;
constexpr size_t O_XG2  = 59904;
constexpr size_t O_XWG2 = 92672;
constexpr size_t O_YG2  = 125440;
constexpr size_t O_XG3  = 256512;
constexpr size_t O_XW3  = 387584;
constexpr size_t O_YG3  = 399872;
constexpr size_t O_DEG  = 449024;
constexpr size_t O_RP   = 470784;
constexpr size_t O_CUR  = 492548;
constexpr size_t O_EIDX = 514312;
constexpr size_t O_XL   = 645120;
constexpr size_t O_YL0  = 1169408;
constexpr size_t O_XL1  = 1693696;
constexpr size_t O_YL1  = 2217984;
constexpr size_t O_XL2  = 2742272;
constexpr size_t O_YL2  = 3266560;
constexpr size_t O_XL3  = 3790848;
constexpr size_t O_YL3  = 4315136;
constexpr size_t O_BAR  = 4364288;

struct Params {
    const float *z, *lin_w, *lin_b, *loc_w, *loc_b, *Wg, *bg, *Wg3, *bg3;
    const float *Wl, *bl, *Wl3, *bl3, *gam_g, *bet_g, *gam_l, *bet_l;
    const float *U0, *U1, *U2, *U3;
    const int *A0, *A1, *A2, *A3;
    float* ws;
    float* out;
};

// grid barrier (mechanism proven correct R6; cost is not the bottleneck)
__device__ __forceinline__ void gbar(int* bars, int idx) {
    __syncthreads();
    if (threadIdx.x == 0) {
        __threadfence();
        atomicAdd(bars + idx, 1);
        int it = 0;
        while (true) {
            int v;
            if ((++it & 31) == 0)
                v = atomicAdd(bars + idx, 0);
            else
                v = __hip_atomic_load(bars + idx, __ATOMIC_RELAXED,
                                      __HIP_MEMORY_SCOPE_SYSTEM);
            if (v >= NB) break;
            __builtin_amdgcn_s_sleep(2);
        }
    }
    __syncthreads();
    __threadfence();
}

// pre-kernel: zero barriers/stats/deg; block 64 computes the linear head
__global__ void __launch_bounds__(256) k_pre(const float* __restrict__ z,
                                             const float* __restrict__ lin_w,
                                             const float* __restrict__ lin_b,
                                             const float* __restrict__ Wg0,
                                             float* __restrict__ ws) {
    int t = threadIdx.x, b = blockIdx.x;
    if (b < 64) {
        int* deg = (int*)(ws + O_DEG);
        for (int i = b * 256 + t; i < 21760; i += 64 * 256) deg[i] = 0;
        if (b == 0 && t < 32) ((int*)(ws + O_BAR))[t] = 0;
        if (b == 1) for (int i = t; i < 384; i += 256) (ws + O_STAT)[i] = 0.f;
        return;
    }
    __shared__ float zl[128];
    __shared__ float xl[160];
    __shared__ float xwl[32];
    if (t < 128) zl[t] = z[t];
    __syncthreads();
    if (t < 160) {
        float s = lin_b[t];
        for (int k = 0; k < 128; k++) s += zl[k] * lin_w[k * 160 + t];
        xl[t] = s;
    }
    __syncthreads();
    if (t < 128) (ws + O_XLZ)[t] = xl[32 + t];
    if (t < 32) {
        float s = 0.f;
        for (int k = 0; k < 32; k++) s += xl[k] * Wg0[k * 32 + t];
        xwl[t] = s;
    }
    __syncthreads();
    for (int i = t; i < 2048; i += 256) (ws + O_XW0)[i] = xwl[i & 31];
}

// 268MB streaming matvec slice (1024 threads)
__device__ void matvec_slice(const Params& P, int i0, int i1, int rb, int nrb,
                             float* smem) {
    int t = threadIdx.x;
    float* xs = smem;
    if (t < 128) xs[t] = (P.ws + O_XLZ)[t];
    __syncthreads();
    float* y = P.ws + O_XL;
    for (int i = i0 + rb * NT + t; i < i1; i += nrb * NT) {
        int j0 = i * 4;
        float4 acc = *(const float4*)(P.loc_b + j0);
#pragma unroll 8
        for (int k = 0; k < 128; k++) {
            float xk = xs[k];
            float4 w = *(const float4*)(P.loc_w + (size_t)k * LOCN + j0);
            acc.x += xk * w.x; acc.y += xk * w.y; acc.z += xk * w.z; acc.w += xk * w.w;
        }
        *(float4*)(y + j0) = acc;
    }
    __syncthreads();
}

// pull feast (F=32) + bias + BN-stat partial reduce; 32 node-groups/block
__device__ void gather_f(const int* rp, const int* ei, const float* y,
                         const float* bias, int n, float* xout, float* stats,
                         int rb, int nrb, float* smem) {
    float* red  = smem;
    float* red2 = smem + 1024;
    int t = threadIdx.x, f = t & 31, g = t >> 5;
    float bf = bias[f];
    float s = 0.f, ss = 0.f;
    for (int node = rb * 32 + g; node < n; node += nrb * 32) {
        int r0 = rp[node], r1 = rp[node + 1];
        float a = y[(size_t)node * 32 + f];
        int r = r0;
        for (; r + 4 <= r1; r += 4) {
            int s0 = ei[r], s1 = ei[r + 1], s2 = ei[r + 2], s3 = ei[r + 3];
            a += y[(size_t)s0 * 32 + f] + y[(size_t)s1 * 32 + f] +
                 y[(size_t)s2 * 32 + f] + y[(size_t)s3 * 32 + f];
        }
        for (; r < r1; r++) a += y[(size_t)ei[r] * 32 + f];
        float v = a / (float)(r1 - r0 + 1) + bf;
        xout[(size_t)node * 32 + f] = v;
        s += v; ss += v * v;
    }
    red[t] = s; red2[t] = ss;
    __syncthreads();
    if (t < 32) {
        float a = 0.f, b = 0.f;
#pragma unroll
        for (int j = 0; j < 32; j++) { a += red[t + 32 * j]; b += red2[t + 32 * j]; }
        atomicAdd(stats + t, a);
        atomicAdd(stats + 32 + t, b);
    }
    __syncthreads();
}

// per-node optional BN+leakyReLU then row @ W(32xFO); 1024 threads
template <int FO>
__device__ void bnxw_f(const float* xin, const float* stats, const float* gam,
                       const float* bet, const float* W, float invn, int n,
                       float* out, int rb, int nrb, bool do_bn, float* smem) {
    float* Wl = smem;
    float* sc = smem + 32 * FO;
    float* sh = sc + 32;
    int t = threadIdx.x;
    if (t < 32 * FO) Wl[t] = W[t];
    if (t >= 512 && t < 544) {
        int q = t - 512;
        if (do_bn) {
            float mu = stats[q] * invn;
            float var = stats[32 + q] * invn - mu * mu;
            float rs = rsqrtf(var + 1e-5f);
            float scv = rs * gam[q];
            sc[q] = scv; sh[q] = bet[q] - mu * scv;
        } else { sc[q] = 1.f; sh[q] = 0.f; }
    }
    __syncthreads();
    for (int node = rb * NT + t; node < n; node += nrb * NT) {
        float x[32];
        const float4* xp = (const float4*)(xin + (size_t)node * 32);
#pragma unroll
        for (int j = 0; j < 8; j++) {
            float4 v = xp[j];
            x[4 * j] = v.x; x[4 * j + 1] = v.y; x[4 * j + 2] = v.z; x[4 * j + 3] = v.w;
        }
        if (do_bn) {
#pragma unroll
            for (int k = 0; k < 32; k++) {
                float v = sc[k] * x[k] + sh[k];
                x[k] = v > 0.f ? v : 0.01f * v;
            }
        }
        float yv[FO];
#pragma unroll
        for (int q = 0; q < FO; q++) {
            float s = 0.f;
#pragma unroll
            for (int k = 0; k < 32; k++) s += x[k] * Wl[k * FO + q];
            yv[q] = s;
        }
        float* yp = out + (size_t)node * FO;
#pragma unroll
        for (int q = 0; q < FO; q++) yp[q] = yv[q];
    }
    __syncthreads();
}

// y = U(64 rows) @ xw(m x 32); 1024 threads, K staged in 64-chunks
__device__ void gemm32_f(const float* U, const float* xw, int m, float* y,
                         int rb, float* smem) {
    float* ut = smem;        // 64*64
    float* xt = smem + 4096; // 64*32
    int t = threadIdx.x;
    int r0 = rb * 64;
    int f = t & 31, rg = t >> 5; // rg 0..31
    float a0 = 0, a1 = 0;
    for (int k0 = 0; k0 < m; k0 += 64) {
        {
            int row = t >> 4, c0 = (t & 15) * 4;
            *(float4*)(ut + row * 64 + c0) =
                *(const float4*)(U + (size_t)(r0 + row) * m + k0 + c0);
        }
        if (t < 512) {
            int kk = t >> 3, c0 = (t & 7) * 4;
            *(float4*)(xt + kk * 32 + c0) =
                *(const float4*)(xw + (size_t)(k0 + kk) * 32 + c0);
        }
        __syncthreads();
#pragma unroll
        for (int kk = 0; kk < 64; kk++) {
            float xv = xt[kk * 32 + f];
            a0 += ut[rg * 64 + kk] * xv;
            a1 += ut[(rg + 32) * 64 + kk] * xv;
        }
        __syncthreads();
    }
    y[(r0 + rg) * 32 + f] = a0;
    y[(r0 + rg + 32) * 32 + f] = a1;
}

__global__ void __launch_bounds__(NT, 1) mega(Params P) {
    __shared__ float smem[12288];
    int t = threadIdx.x, bid = blockIdx.x;
    float* ws = P.ws;
    int* deg  = (int*)(ws + O_DEG);
    int* rp   = (int*)(ws + O_RP);
    int* cur  = (int*)(ws + O_CUR);
    int* eidx = (int*)(ws + O_EIDX);
    int* bars = (int*)(ws + O_BAR);

    // ---------- P1: deg histogram | gemm_g0 (U3) | matvec slice 0 ----------
    if (bid < 16) {
        for (int e = bid * NT + t; e < ETOT; e += 16 * NT) {
            const int* A; int E, dofs; int x = e;
            if (x < E0)              { A = P.A0; E = E0; dofs = 0; }
            else if ((x -= E0) < E1) { A = P.A1; E = E1; dofs = 16384; }
            else if ((x -= E1) < E2) { A = P.A2; E = E2; dofs = 20480; }
            else { x -= E2;            A = P.A3; E = E3; dofs = 21504; }
            atomicAdd(deg + dofs + A[E + x], 1);
        }
    } else if (bid == 16) {
        for (int i = t; i < 2048; i += NT) smem[i] = (ws + O_XW0)[i];
        __syncthreads();
        if (t < 256) {
            float acc[32];
#pragma unroll
            for (int f = 0; f < 32; f++) acc[f] = 0.f;
            int r = t;
            for (int k = 0; k < 64; k++) {
                float u = P.U3[r * 64 + k];
#pragma unroll
                for (int f = 0; f < 32; f++) acc[f] += u * smem[k * 32 + f];
            }
            float* yp = ws + O_YG0 + r * 32;
#pragma unroll
            for (int f = 0; f < 32; f++) yp[f] = acc[f];
        }
    } else {
        matvec_slice(P, 0, 43691, bid - 17, 239, smem);
    }
    gbar(bars, 0);

    // ---------- P2: scan (4 blocks) | matvec slice 1 ----------
    if (bid < 4) {
        int n  = bid == 0 ? N0 : bid == 1 ? N1 : bid == 2 ? N2 : N3;
        int db = bid == 0 ? 0 : bid == 1 ? 16384 : bid == 2 ? 20480 : 21504;
        int rb = bid == 0 ? 0 : bid == 1 ? 16385 : bid == 2 ? 20482 : 21507;
        int per = (n + NT - 1) / NT;
        const int* d = deg + db;
        int* rpp = rp + rb;
        int* cup = cur + rb;
        int loc[16];
        int s = 0;
        for (int i = 0; i < per; i++) {
            int idx = t * per + i;
            int v = (idx < n) ? d[idx] : 0;
            loc[i] = s; s += v;
        }
        int* part = (int*)smem;
        part[t] = s;
        __syncthreads();
        for (int off = 1; off < NT; off <<= 1) {
            int v = (t >= off) ? part[t - off] : 0;
            __syncthreads();
            part[t] += v;
            __syncthreads();
        }
        int excl = t ? part[t - 1] : 0;
        for (int i = 0; i < per; i++) {
            int idx = t * per + i;
            if (idx < n) { rpp[idx] = excl + loc[i]; cup[idx] = excl + loc[i]; }
        }
        if (t == NT - 1) rpp[n] = part[NT - 1];
    } else {
        matvec_slice(P, 43691, 87382, bid - 4, 252, smem);
    }
    gbar(bars, 1);

    // ---------- P3: CSR fill | matvec slice 2 ----------
    if (bid < 16) {
        for (int e = bid * NT + t; e < ETOT; e += 16 * NT) {
            const int* A; int E, cofs, eofs; int x = e;
            if (x < E0)              { A = P.A0; E = E0; cofs = 0;     eofs = 0; }
            else if ((x -= E0) < E1) { A = P.A1; E = E1; cofs = 16385; eofs = 98304; }
            else if ((x -= E1) < E2) { A = P.A2; E = E2; cofs = 20482; eofs = 122880; }
            else { x -= E2;            A = P.A3; E = E3; cofs = 21507; eofs = 129024; }
            int srcn = A[x], dd = A[E + x];
            int slot = atomicAdd(cur + cofs + dd, 1);
            eidx[eofs + slot] = srcn;
        }
    } else {
        matvec_slice(P, 87382, 131072, bid - 16, 240, smem);
    }
    gbar(bars, 2);

    // ---------- P4: y_l0 = xl @ Wl0 | gather_g0 (A3) ----------
    if (bid < 240)
        bnxw_f<32>(ws + O_XL, nullptr, nullptr, nullptr, P.Wl, 0.f, N0,
                   ws + O_YL0, bid, 240, false, smem);
    else
        gather_f(rp + 21507, eidx + 129024, ws + O_YG0, P.bg, N3,
                 ws + O_XG1, ws + O_STAT, bid - 240, 16, smem);
    gbar(bars, 3);

    // ---------- P5: gather_l0 (A0) | bnxw_g0 ----------
    if (bid < 240)
        gather_f(rp, eidx, ws + O_YL0, P.bl, N0, ws + O_XL1, ws + O_STAT + 192,
                 bid, 240, smem);
    else
        bnxw_f<32>(ws + O_XG1, ws + O_STAT, P.gam_g, P.bet_g, P.Wg + 1024,
                   1.f / N3, N3, ws + O_XWG1, bid - 240, 16, true, smem);
    gbar(bars, 4);

    // ---------- P6: bnxw_l0 | gemm_g1 (U2: 1024x256, 16 blocks of 64 rows) ----------
    if (bid < 224)
        bnxw_f<32>(ws + O_XL1, ws + O_STAT + 192, P.gam_l, P.bet_l, P.Wl + 1024,
                   1.f / N0, N0, ws + O_YL1, bid, 224, true, smem);
    else if (bid < 240)
        gemm32_f(P.U2, ws + O_XWG1, 256, ws + O_YG1, bid - 224, smem);
    gbar(bars, 5);

    // ---------- P7: gather_l1 | gather_g1 (A2) ----------
    if (bid < 240)
        gather_f(rp, eidx, ws + O_YL1, P.bl + 32, N0, ws + O_XL2,
                 ws + O_STAT + 256, bid, 240, smem);
    else
        gather_f(rp + 20482, eidx + 122880, ws + O_YG1, P.bg + 32, N2,
                 ws + O_XG2, ws + O_STAT + 64, bid - 240, 16, smem);
    gbar(bars, 6);

    // ---------- P8: bnxw_l1 | bnxw_g1 ----------
    if (bid < 240)
        bnxw_f<32>(ws + O_XL2, ws + O_STAT + 256, P.gam_l + 32, P.bet_l + 32,
                   P.Wl + 2048, 1.f / N0, N0, ws + O_YL2, bid, 240, true, smem);
    else
        bnxw_f<32>(ws + O_XG2, ws + O_STAT + 64, P.gam_g + 32, P.bet_g + 32,
                   P.Wg + 2048, 1.f / N2, N2, ws + O_XWG2, bid - 240, 16, true, smem);
    gbar(bars, 7);

    // ---------- P9: gather_l2 | gemm_g2 (U1: 4096x1024, 64 blocks of 64 rows) ----------
    if (bid < 192)
        gather_f(rp, eidx, ws + O_YL2, P.bl + 64, N0, ws + O_XL3,
                 ws + O_STAT + 320, bid, 192, smem);
    else
        gemm32_f(P.U1, ws + O_XWG2, 1024, ws + O_YG2, bid - 192, smem);
    gbar(bars, 8);

    // ---------- P10: bnxw_l2 (FO=3 -> y_l3) | gather_g2 (A1) ----------
    if (bid < 64)
        bnxw_f<3>(ws + O_XL3, ws + O_STAT + 320, P.gam_l + 64, P.bet_l + 64,
                  P.Wl3, 1.f / N0, N0, ws + O_YL3, bid, 64, true, smem);
    else
        gather_f(rp + 16385, eidx + 98304, ws + O_YG2, P.bg + 64, N1,
                 ws + O_XG3, ws + O_STAT + 128, bid - 64, 192, smem);
    gbar(bars, 9);

    // ---------- P11: bnxw_g2 (FO=3 -> xw3) ----------
    if (bid < 16)
        bnxw_f<3>(ws + O_XG3, ws + O_STAT + 128, P.gam_g + 64, P.bet_g + 64,
                  P.Wg3, 1.f / N1, N1, ws + O_XW3, bid, 16, true, smem);
    gbar(bars, 10);

    // ---------- P12: yg3 = U0 @ xw3 (268 MB stream, 64 rows/block, 16 waves) ----------
    {
        const float* xw3 = ws + O_XW3;
        float* y = ws + O_YG3;
        for (int i = t; i < 12288; i += NT) {
            int k = i / 3, h = i - 3 * k;
            smem[h * 4096 + ((k & 3) << 10) + (k >> 2)] = xw3[i];
        }
        __syncthreads();
        int w = t >> 6, lane = t & 63;
        for (int rr = 0; rr < 4; rr++) {
            int row = bid * 64 + w * 4 + rr;
            const float4* up = (const float4*)(P.U0 + (size_t)row * 4096);
            float a0 = 0, a1 = 0, a2 = 0;
#pragma unroll 8
            for (int c = 0; c < 16; c++) {
                float4 u = up[c * 64 + lane];
                int b = c * 64 + lane;
                a0 += u.x * smem[b]        + u.y * smem[1024 + b]  + u.z * smem[2048 + b]   + u.w * smem[3072 + b];
                a1 += u.x * smem[4096 + b] + u.y * smem[5120 + b]  + u.z * smem[6144 + b]   + u.w * smem[7168 + b];
                a2 += u.x * smem[8192 + b] + u.y * smem[9216 + b]  + u.z * smem[10240 + b]  + u.w * smem[11264 + b];
            }
            for (int o = 32; o; o >>= 1) {
                a0 += __shfl_down(a0, o, 64);
                a1 += __shfl_down(a1, o, 64);
                a2 += __shfl_down(a2, o, 64);
            }
            if (lane == 0) { y[row * 3] = a0; y[row * 3 + 1] = a1; y[row * 3 + 2] = a2; }
        }
    }
    gbar(bars, 11);

    // ---------- P13: final combine over A0 ----------
    {
        int i = bid * NT + t;
        if (i < 49152) {
            int node = i / 3, r = i - 3 * node;
            const float* yg = ws + O_YG3;
            const float* yl = ws + O_YL3;
            int r0 = rp[node], r1 = rp[node + 1];
            float ag = yg[node * 3 + r], al = yl[node * 3 + r];
            int e = r0;
            for (; e + 4 <= r1; e += 4) {
                int s0 = eidx[e], s1 = eidx[e + 1], s2 = eidx[e + 2], s3 = eidx[e + 3];
                ag += yg[s0 * 3 + r] + yg[s1 * 3 + r] + yg[s2 * 3 + r] + yg[s3 * 3 + r];
                al += yl[s0 * 3 + r] + yl[s1 * 3 + r] + yl[s2 * 3 + r] + yl[s3 * 3 + r];
            }
            for (; e < r1; e++) { ag += yg[eidx[e] * 3 + r]; al += yl[eidx[e] * 3 + r]; }
            float inv = 1.f / (float)(r1 - r0 + 1);
            P.out[node * 3 + r] = 0.01f * (ag * inv + P.bg3[r]) + 0.99f * (al * inv + P.bl3[r]);
        }
    }
}

extern "C" void kernel_launch(void* const* d_in, const int* in_sizes, int n_in,
                              void* d_out, int out_size, void* d_ws, size_t ws_size,
                              hipStream_t stream) {
    Params p;
    p.z     = (const float*)d_in[0];
    p.lin_w = (const float*)d_in[1];
    p.lin_b = (const float*)d_in[2];
    p.loc_w = (const float*)d_in[3];
    p.loc_b = (const float*)d_in[4];
    p.Wg    = (const float*)d_in[5];
    p.bg    = (const float*)d_in[8];
    p.Wg3   = (const float*)d_in[9];
    p.bg3   = (const float*)d_in[12];
    p.Wl    = (const float*)d_in[13];
    p.bl    = (const float*)d_in[16];
    p.Wl3   = (const float*)d_in[17];
    p.bl3   = (const float*)d_in[20];
    p.gam_g = (const float*)d_in[21];
    p.bet_g = (const float*)d_in[22];
    p.gam_l = (const float*)d_in[23];
    p.bet_l = (const float*)d_in[24];
    p.U0    = (const float*)d_in[25];
    p.U1    = (const float*)d_in[26];
    p.U2    = (const float*)d_in[27];
    p.U3    = (const float*)d_in[28];
    p.A0    = (const int*)d_in[29];
    p.A1    = (const int*)d_in[30];
    p.A2    = (const int*)d_in[31];
    p.A3    = (const int*)d_in[32];
    p.ws    = (float*)d_ws;
    p.out   = (float*)d_out;

    k_pre<<<65, 256, 0, stream>>>(p.z, p.lin_w, p.lin_b, p.Wg, p.ws);
    mega<<<NB, NT, 0, stream>>>(p);
}

// Round 8
// 497.077 us; speedup vs baseline: 2.9389x; 2.9389x over previous
//
#include <hip/hip_runtime.h>
#include <cstddef>

constexpr int N0 = 16384, N1 = 4096, N2 = 1024, N3 = 256;
constexpr int E0 = 6 * N0, E1 = 6 * N1, E2 = 6 * N2, E3 = 6 * N3;
constexpr int ETOT = E0 + E1 + E2 + E3; // 129024
constexpr int LOCN = 32 * N0;           // 524288

// ---- workspace layout (float offsets) ----
constexpr size_t O_XLZ  = 0;
constexpr size_t O_STAT = 128;      // 6 slots x 64 (sum|sumsq)
constexpr size_t O_XW0  = 512;      // 64x32 bcast
constexpr size_t O_YG0  = 2560;     // 256x32
constexpr size_t O_XG1  = 10752;
constexpr size_t O_XWG1 = 18944;
constexpr size_t O_YG1  = 27136;    // 1024x32
constexpr size_t O_XG2  = 59904;
constexpr size_t O_XWG2 = 92672;
constexpr size_t O_YG2  = 125440;   // 4096x32
constexpr size_t O_XG3  = 256512;
constexpr size_t O_XW3  = 387584;   // 4096x3
constexpr size_t O_YG3  = 399872;   // 16384x3
constexpr size_t O_DEG  = 449024;   // ints
constexpr size_t O_RP   = 470784;
constexpr size_t O_CUR  = 492548;
constexpr size_t O_EIDX = 514312;
constexpr size_t O_YL0  = 1169408;  // 16384x32
constexpr size_t O_XL1  = 1693696;
constexpr size_t O_YL1  = 2217984;
constexpr size_t O_XL2  = 2742272;
constexpr size_t O_YL2  = 3266560;
constexpr size_t O_XL3  = 3790848;
constexpr size_t O_YL3  = 4315136;  // 16384x3

struct Params {
    const float *z, *lin_w, *lin_b, *loc_w, *loc_b, *Wg, *bg, *Wg3, *bg3;
    const float *Wl, *bl, *Wl3, *bl3, *gam_g, *bet_g, *gam_l, *bet_l;
    const float *U0, *U1, *U2, *U3;
    const int *A0, *A1, *A2, *A3;
    float* ws;
    float* out;
};

// ================= K1: pre (zero deg/stats + linear head) =================
__global__ void __launch_bounds__(256) k_pre(Params P) {
    int t = threadIdx.x, b = blockIdx.x;
    float* ws = P.ws;
    if (b < 64) {
        int* deg = (int*)(ws + O_DEG);
        for (int i = b * 256 + t; i < 21760; i += 64 * 256) deg[i] = 0;
        if (b == 1) for (int i = t; i < 384; i += 256) (ws + O_STAT)[i] = 0.f;
        return;
    }
    __shared__ float zl[128];
    __shared__ float xl[160];
    __shared__ float xwl[32];
    if (t < 128) zl[t] = P.z[t];
    __syncthreads();
    if (t < 160) {
        float s = P.lin_b[t];
        for (int k = 0; k < 128; k++) s += zl[k] * P.lin_w[k * 160 + t];
        xl[t] = s;
    }
    __syncthreads();
    if (t < 128) (ws + O_XLZ)[t] = xl[32 + t];
    if (t < 32) {
        float s = 0.f;
        for (int k = 0; k < 32; k++) s += xl[k] * P.Wg[k * 32 + t];
        xwl[t] = s;
    }
    __syncthreads();
    for (int i = t; i < 2048; i += 256) (ws + O_XW0)[i] = xwl[i & 31];
}

// ============ device: fused matvec + @Wl0 (one 32-node chunk) ============
// y_l0[mb*1024 .. +1024) = ((xlz @ loc_w + loc_b) rows) @ Wl0
__device__ void matvec_y(const Params& P, int mb, float* sm) {
    float* xs = sm;          // 128
    float* xrow = sm + 128;  // 1024
    float* Wl = sm + 1152;   // 1024
    int t = threadIdx.x;
    if (t < 128) xs[t] = (P.ws + O_XLZ)[t];
    for (int i = t; i < 1024; i += 256) Wl[i] = P.Wl[i];
    __syncthreads();
    size_t j0 = (size_t)mb * 1024 + t * 4;
    float4 acc = *(const float4*)(P.loc_b + j0);
#pragma unroll 8
    for (int k = 0; k < 128; k++) {
        float xk = xs[k];
        float4 w = *(const float4*)(P.loc_w + (size_t)k * LOCN + j0);
        acc.x += xk * w.x; acc.y += xk * w.y; acc.z += xk * w.z; acc.w += xk * w.w;
    }
    *(float4*)(xrow + t * 4) = acc;
    __syncthreads();
    float* yl0 = P.ws + O_YL0;
#pragma unroll
    for (int q = 0; q < 4; q++) {
        int idx = q * 256 + t;
        int nn = idx >> 5, f = idx & 31;
        float s = 0.f;
        const float* xr = xrow + nn * 32;
#pragma unroll
        for (int k = 0; k < 32; k++) s += xr[k] * Wl[k * 32 + f];
        yl0[(size_t)mb * 1024 + idx] = s;
    }
}

// ================= K2: deg histogram | U3 gemm | matvec[0:171] =================
__global__ void __launch_bounds__(256) k_l2(Params P) {
    __shared__ float sm[2304];
    int t = threadIdx.x, bid = blockIdx.x;
    float* ws = P.ws;
    if (bid < 64) {
        int* deg = (int*)(ws + O_DEG);
        for (int e = bid * 256 + t; e < ETOT; e += 64 * 256) {
            const int* A; int E, dofs; int x = e;
            if (x < E0)              { A = P.A0; E = E0; dofs = 0; }
            else if ((x -= E0) < E1) { A = P.A1; E = E1; dofs = 16384; }
            else if ((x -= E1) < E2) { A = P.A2; E = E2; dofs = 20480; }
            else { x -= E2;            A = P.A3; E = E3; dofs = 21504; }
            atomicAdd(deg + dofs + A[E + x], 1);
        }
    } else if (bid == 64) {
        for (int i = t; i < 2048; i += 256) sm[i] = (ws + O_XW0)[i];
        __syncthreads();
        float acc[32];
#pragma unroll
        for (int f = 0; f < 32; f++) acc[f] = 0.f;
        for (int k = 0; k < 64; k++) {
            float u = P.U3[t * 64 + k];
#pragma unroll
            for (int f = 0; f < 32; f++) acc[f] += u * sm[k * 32 + f];
        }
        float* yp = ws + O_YG0 + t * 32;
#pragma unroll
        for (int f = 0; f < 32; f++) yp[f] = acc[f];
    } else {
        matvec_y(P, bid - 65, sm);
    }
}

// ================= K3: scan (4 blocks) | matvec[171:342] =================
__global__ void __launch_bounds__(256) k_l3(Params P) {
    __shared__ float sm[2304];
    int t = threadIdx.x, bid = blockIdx.x;
    float* ws = P.ws;
    if (bid < 4) {
        int n   = bid == 0 ? N0 : bid == 1 ? N1 : bid == 2 ? N2 : N3;
        int db  = bid == 0 ? 0 : bid == 1 ? 16384 : bid == 2 ? 20480 : 21504;
        int rbo = bid == 0 ? 0 : bid == 1 ? 16385 : bid == 2 ? 20482 : 21507;
        int per = n >> 8;
        const int* d = (int*)(ws + O_DEG) + db;
        int* rpp = (int*)(ws + O_RP) + rbo;
        int* cup = (int*)(ws + O_CUR) + rbo;
        int s = 0;
        for (int i = 0; i < per; i++) s += d[t * per + i];
        int* part = (int*)sm;
        part[t] = s;
        __syncthreads();
        for (int off = 1; off < 256; off <<= 1) {
            int v = (t >= off) ? part[t - off] : 0;
            __syncthreads();
            part[t] += v;
            __syncthreads();
        }
        int run = t ? part[t - 1] : 0;
        for (int i = 0; i < per; i++) {
            int idx = t * per + i;
            rpp[idx] = run; cup[idx] = run;
            run += d[idx];
        }
        if (t == 255) rpp[n] = part[255];
    } else {
        matvec_y(P, bid - 4 + 171, sm);
    }
}

// ================= K4: CSR fill | matvec[342:512] =================
__global__ void __launch_bounds__(256) k_l4(Params P) {
    __shared__ float sm[2304];
    int t = threadIdx.x, bid = blockIdx.x;
    float* ws = P.ws;
    if (bid < 64) {
        int* cur  = (int*)(ws + O_CUR);
        int* eidx = (int*)(ws + O_EIDX);
        for (int e = bid * 256 + t; e < ETOT; e += 64 * 256) {
            const int* A; int E, cofs, eofs; int x = e;
            if (x < E0)              { A = P.A0; E = E0; cofs = 0;     eofs = 0; }
            else if ((x -= E0) < E1) { A = P.A1; E = E1; cofs = 16385; eofs = 98304; }
            else if ((x -= E1) < E2) { A = P.A2; E = E2; cofs = 20482; eofs = 122880; }
            else { x -= E2;            A = P.A3; E = E3; cofs = 21507; eofs = 129024; }
            int srcn = A[x], dd = A[E + x];
            int slot = atomicAdd(cur + cofs + dd, 1);
            eidx[eofs + slot] = srcn;
        }
    } else {
        matvec_y(P, bid - 64 + 342, sm);
    }
}

// ============ device: pull gather (F=32) + bias + BN stats ============
// one wave per node; lanes 0-31 handle self+even edges, 32-63 odd edges
__device__ void gather512(const int* rp, const int* ei, const float* y,
                          const float* bias, int n, float* xout, float* stats,
                          int rb, float* sm) {
    int t = threadIdx.x, f = t & 31, half = (t >> 5) & 1, w = t >> 6;
    if (t < 64) sm[t] = 0.f;
    __syncthreads();
    int node = rb * 8 + w;
    if (node < n) {
        int r0 = rp[node], r1 = rp[node + 1];
        float a = half ? 0.f : y[(size_t)node * 32 + f];
        for (int r = r0 + half; r < r1; r += 2)
            a += y[(size_t)ei[r] * 32 + f];
        a += __shfl_down(a, 32, 64);
        if (!half) {
            float v = a / (float)(r1 - r0 + 1) + bias[f];
            xout[(size_t)node * 32 + f] = v;
            atomicAdd(sm + f, v);
            atomicAdd(sm + 32 + f, v * v);
        }
    }
    __syncthreads();
    if (t < 64) atomicAdd(stats + t, sm[t]);
}

// ============ device: BN + leakyReLU + row @ W(32xFO), 512 threads ============
template <int FO>
__device__ void bnxw512(const float* xin, const float* stats, const float* gam,
                        const float* bet, const float* W, float invn, int n,
                        float* out, int rb, float* sm) {
    float* Wl = sm;
    float* sc = sm + 32 * FO;
    float* sh = sc + 32;
    int t = threadIdx.x;
    for (int i = t; i < 32 * FO; i += 512) Wl[i] = W[i];
    if (t < 32) {
        float mu = stats[t] * invn;
        float var = stats[32 + t] * invn - mu * mu;
        float rs = rsqrtf(var + 1e-5f);
        float scv = rs * gam[t];
        sc[t] = scv; sh[t] = bet[t] - mu * scv;
    }
    __syncthreads();
    int node = rb * 512 + t;
    if (node < n) {
        float x[32];
        const float4* xp = (const float4*)(xin + (size_t)node * 32);
#pragma unroll
        for (int j = 0; j < 8; j++) {
            float4 v = xp[j];
            x[4 * j] = v.x; x[4 * j + 1] = v.y; x[4 * j + 2] = v.z; x[4 * j + 3] = v.w;
        }
#pragma unroll
        for (int k = 0; k < 32; k++) {
            float v = sc[k] * x[k] + sh[k];
            x[k] = v > 0.f ? v : 0.01f * v;
        }
        float yv[FO];
#pragma unroll
        for (int q = 0; q < FO; q++) {
            float s = 0.f;
#pragma unroll
            for (int k = 0; k < 32; k++) s += x[k] * Wl[k * FO + q];
            yv[q] = s;
        }
        float* yp = out + (size_t)node * FO;
#pragma unroll
        for (int q = 0; q < FO; q++) yp[q] = yv[q];
    }
}

// ============ device: y = U(64 rows) @ xw(m x 32), 512 threads ============
__device__ void gemm512(const float* U, const float* xw, int m, float* y,
                        int rb, float* sm) {
    float* ut = sm;          // 64*64
    float* xt = sm + 4096;   // 64*32
    int t = threadIdx.x, f = t & 31, rg = t >> 5; // rg 0..15
    int r0 = rb * 64;
    float a0 = 0, a1 = 0, a2 = 0, a3 = 0;
    for (int k0 = 0; k0 < m; k0 += 64) {
        {
            int row = t >> 3, c0 = (t & 7) * 8;
            const float* src = U + (size_t)(r0 + row) * m + k0 + c0;
            *(float4*)(ut + row * 64 + c0) = *(const float4*)src;
            *(float4*)(ut + row * 64 + c0 + 4) = *(const float4*)(src + 4);
        }
        {
            int kk = t >> 3, c0 = (t & 7) * 4;
            *(float4*)(xt + kk * 32 + c0) =
                *(const float4*)(xw + (size_t)(k0 + kk) * 32 + c0);
        }
        __syncthreads();
#pragma unroll
        for (int kk = 0; kk < 64; kk++) {
            float xv = xt[kk * 32 + f];
            a0 += ut[rg * 64 + kk] * xv;
            a1 += ut[(rg + 16) * 64 + kk] * xv;
            a2 += ut[(rg + 32) * 64 + kk] * xv;
            a3 += ut[(rg + 48) * 64 + kk] * xv;
        }
        __syncthreads();
    }
    y[(size_t)(r0 + rg) * 32 + f] = a0;
    y[(size_t)(r0 + rg + 16) * 32 + f] = a1;
    y[(size_t)(r0 + rg + 32) * 32 + f] = a2;
    y[(size_t)(r0 + rg + 48) * 32 + f] = a3;
}

// ================= K5: gather_l0 | gather_g0 =================
__global__ void __launch_bounds__(512) k_l5(Params P) {
    __shared__ float sm[64];
    int bid = blockIdx.x;
    float* ws = P.ws;
    const int* rp = (int*)(ws + O_RP);
    const int* ei = (int*)(ws + O_EIDX);
    if (bid < 2048)
        gather512(rp, ei, ws + O_YL0, P.bl, N0, ws + O_XL1, ws + O_STAT + 192, bid, sm);
    else
        gather512(rp + 21507, ei + 129024, ws + O_YG0, P.bg, N3, ws + O_XG1,
                  ws + O_STAT, bid - 2048, sm);
}

// ================= K6: bnxw_l0 | bnxw_g0 =================
__global__ void __launch_bounds__(512) k_l6(Params P) {
    __shared__ float sm[1152];
    int bid = blockIdx.x;
    float* ws = P.ws;
    if (bid < 32)
        bnxw512<32>(ws + O_XL1, ws + O_STAT + 192, P.gam_l, P.bet_l, P.Wl + 1024,
                    1.f / N0, N0, ws + O_YL1, bid, sm);
    else
        bnxw512<32>(ws + O_XG1, ws + O_STAT, P.gam_g, P.bet_g, P.Wg + 1024,
                    1.f / N3, N3, ws + O_XWG1, bid - 32, sm);
}

// ================= K7: gather_l1 | gemm_g1 (U2) =================
__global__ void __launch_bounds__(512) k_l7(Params P) {
    __shared__ float sm[6144];
    int bid = blockIdx.x;
    float* ws = P.ws;
    const int* rp = (int*)(ws + O_RP);
    const int* ei = (int*)(ws + O_EIDX);
    if (bid < 2048)
        gather512(rp, ei, ws + O_YL1, P.bl + 32, N0, ws + O_XL2,
                  ws + O_STAT + 256, bid, sm);
    else
        gemm512(P.U2, ws + O_XWG1, 256, ws + O_YG1, bid - 2048, sm);
}

// ================= K8: bnxw_l1 | gather_g1 =================
__global__ void __launch_bounds__(512) k_l8(Params P) {
    __shared__ float sm[1152];
    int bid = blockIdx.x;
    float* ws = P.ws;
    const int* rp = (int*)(ws + O_RP);
    const int* ei = (int*)(ws + O_EIDX);
    if (bid < 32)
        bnxw512<32>(ws + O_XL2, ws + O_STAT + 256, P.gam_l + 32, P.bet_l + 32,
                    P.Wl + 2048, 1.f / N0, N0, ws + O_YL2, bid, sm);
    else
        gather512(rp + 20482, ei + 122880, ws + O_YG1, P.bg + 32, N2,
                  ws + O_XG2, ws + O_STAT + 64, bid - 32, sm);
}

// ================= K9: gather_l2 | bnxw_g1 =================
__global__ void __launch_bounds__(512) k_l9(Params P) {
    __shared__ float sm[1152];
    int bid = blockIdx.x;
    float* ws = P.ws;
    const int* rp = (int*)(ws + O_RP);
    const int* ei = (int*)(ws + O_EIDX);
    if (bid < 2048)
        gather512(rp, ei, ws + O_YL2, P.bl + 64, N0, ws + O_XL3,
                  ws + O_STAT + 320, bid, sm);
    else
        bnxw512<32>(ws + O_XG2, ws + O_STAT + 64, P.gam_g + 32, P.bet_g + 32,
                    P.Wg + 2048, 1.f / N2, N2, ws + O_XWG2, bid - 2048, sm);
}

// ================= K10: bnxw_l2 (FO=3) | gemm_g2 (U1) =================
__global__ void __launch_bounds__(512) k_l10(Params P) {
    __shared__ float sm[6144];
    int bid = blockIdx.x;
    float* ws = P.ws;
    if (bid < 32)
        bnxw512<3>(ws + O_XL3, ws + O_STAT + 320, P.gam_l + 64, P.bet_l + 64,
                   P.Wl3, 1.f / N0, N0, ws + O_YL3, bid, sm);
    else
        gemm512(P.U1, ws + O_XWG2, 1024, ws + O_YG2, bid - 32, sm);
}

// ================= K11: gather_g2 =================
__global__ void __launch_bounds__(512) k_l11(Params P) {
    __shared__ float sm[64];
    float* ws = P.ws;
    const int* rp = (int*)(ws + O_RP);
    const int* ei = (int*)(ws + O_EIDX);
    gather512(rp + 16385, ei + 98304, ws + O_YG2, P.bg + 64, N1,
              ws + O_XG3, ws + O_STAT + 128, blockIdx.x, sm);
}

// ================= K12: bnxw_g2 (FO=3) =================
__global__ void __launch_bounds__(512) k_l12(Params P) {
    __shared__ float sm[256];
    bnxw512<3>(P.ws + O_XG3, P.ws + O_STAT + 128, P.gam_g + 64, P.bet_g + 64,
               P.Wg3, 1.f / N1, N1, P.ws + O_XW3, blockIdx.x, sm);
}

// ================= K13: yg3 = U0 @ xw3 (268 MB stream) =================
__global__ void __launch_bounds__(256) k_gemmU3(Params P) {
    __shared__ float pl[3 * 4096];
    int t = threadIdx.x;
    const float* xw3 = P.ws + O_XW3;
    float* y = P.ws + O_YG3;
    for (int i = t; i < 12288; i += 256) {
        int k = i / 3, h = i - 3 * k;
        pl[h * 4096 + ((k & 3) << 10) + (k >> 2)] = xw3[i];
    }
    __syncthreads();
    int w = t >> 6, lane = t & 63;
    for (int rr = 0; rr < 4; rr++) {
        int row = blockIdx.x * 16 + w * 4 + rr;
        const float4* up = (const float4*)(P.U0 + (size_t)row * 4096);
        float a0 = 0, a1 = 0, a2 = 0;
#pragma unroll 4
        for (int c = 0; c < 16; c++) {
            float4 u = up[c * 64 + lane];
            int b = c * 64 + lane;
            a0 += u.x * pl[b]        + u.y * pl[1024 + b]  + u.z * pl[2048 + b]   + u.w * pl[3072 + b];
            a1 += u.x * pl[4096 + b] + u.y * pl[5120 + b]  + u.z * pl[6144 + b]   + u.w * pl[7168 + b];
            a2 += u.x * pl[8192 + b] + u.y * pl[9216 + b]  + u.z * pl[10240 + b]  + u.w * pl[11264 + b];
        }
        for (int o = 32; o; o >>= 1) {
            a0 += __shfl_down(a0, o, 64);
            a1 += __shfl_down(a1, o, 64);
            a2 += __shfl_down(a2, o, 64);
        }
        if (lane == 0) { y[row * 3] = a0; y[row * 3 + 1] = a1; y[row * 3 + 2] = a2; }
    }
}

// ================= K14: final combine over A0 =================
__global__ void __launch_bounds__(256) k_final(Params P) {
    int t = blockIdx.x * 256 + threadIdx.x;
    int node = t >> 2, r = t & 3;
    if (node >= N0 || r >= 3) return;
    float* ws = P.ws;
    const int* rp = (int*)(ws + O_RP);
    const int* ei = (int*)(ws + O_EIDX);
    const float* yg = ws + O_YG3;
    const float* yl = ws + O_YL3;
    int r0 = rp[node], r1 = rp[node + 1];
    float ag = yg[node * 3 + r], al = yl[node * 3 + r];
    int e = r0;
    for (; e + 4 <= r1; e += 4) {
        int s0 = ei[e], s1 = ei[e + 1], s2 = ei[e + 2], s3 = ei[e + 3];
        ag += yg[s0 * 3 + r] + yg[s1 * 3 + r] + yg[s2 * 3 + r] + yg[s3 * 3 + r];
        al += yl[s0 * 3 + r] + yl[s1 * 3 + r] + yl[s2 * 3 + r] + yl[s3 * 3 + r];
    }
    for (; e < r1; e++) { ag += yg[ei[e] * 3 + r]; al += yl[ei[e] * 3 + r]; }
    float inv = 1.f / (float)(r1 - r0 + 1);
    P.out[node * 3 + r] = 0.01f * (ag * inv + P.bg3[r]) + 0.99f * (al * inv + P.bl3[r]);
}

extern "C" void kernel_launch(void* const* d_in, const int* in_sizes, int n_in,
                              void* d_out, int out_size, void* d_ws, size_t ws_size,
                              hipStream_t stream) {
    Params p;
    p.z     = (const float*)d_in[0];
    p.lin_w = (const float*)d_in[1];
    p.lin_b = (const float*)d_in[2];
    p.loc_w = (const float*)d_in[3];
    p.loc_b = (const float*)d_in[4];
    p.Wg    = (const float*)d_in[5];
    p.bg    = (const float*)d_in[8];
    p.Wg3   = (const float*)d_in[9];
    p.bg3   = (const float*)d_in[12];
    p.Wl    = (const float*)d_in[13];
    p.bl    = (const float*)d_in[16];
    p.Wl3   = (const float*)d_in[17];
    p.bl3   = (const float*)d_in[20];
    p.gam_g = (const float*)d_in[21];
    p.bet_g = (const float*)d_in[22];
    p.gam_l = (const float*)d_in[23];
    p.bet_l = (const float*)d_in[24];
    p.U0    = (const float*)d_in[25];
    p.U1    = (const float*)d_in[26];
    p.U2    = (const float*)d_in[27];
    p.U3    = (const float*)d_in[28];
    p.A0    = (const int*)d_in[29];
    p.A1    = (const int*)d_in[30];
    p.A2    = (const int*)d_in[31];
    p.A3    = (const int*)d_in[32];
    p.ws    = (float*)d_ws;
    p.out   = (float*)d_out;

    k_pre   <<<65,   256, 0, stream>>>(p);
    k_l2    <<<236,  256, 0, stream>>>(p);  // hist | U3 gemm | matvec 0:171
    k_l3    <<<175,  256, 0, stream>>>(p);  // scan | matvec 171:342
    k_l4    <<<234,  256, 0, stream>>>(p);  // fill | matvec 342:512
    k_l5    <<<2080, 512, 0, stream>>>(p);  // gather_l0 | gather_g0
    k_l6    <<<33,   512, 0, stream>>>(p);  // bnxw_l0 | bnxw_g0
    k_l7    <<<2064, 512, 0, stream>>>(p);  // gather_l1 | gemm_g1
    k_l8    <<<160,  512, 0, stream>>>(p);  // bnxw_l1 | gather_g1
    k_l9    <<<2050, 512, 0, stream>>>(p);  // gather_l2 | bnxw_g1
    k_l10   <<<96,   512, 0, stream>>>(p);  // bnxw_l2 | gemm_g2
    k_l11   <<<512,  512, 0, stream>>>(p);  // gather_g2
    k_l12   <<<8,    512, 0, stream>>>(p);  // bnxw_g2
    k_gemmU3<<<1024, 256, 0, stream>>>(p);  // U0 @ xw3
    k_final <<<256,  256, 0, stream>>>(p);  // combine
}

// Round 9
// 437.355 us; speedup vs baseline: 3.3403x; 1.1366x over previous
//
#include <hip/hip_runtime.h>
#include <cstddef>

constexpr int N0 = 16384, N1 = 4096, N2 = 1024, N3 = 256;
constexpr int E0 = 6 * N0, E1 = 6 * N1, E2 = 6 * N2, E3 = 6 * N3;
constexpr int ETOT = E0 + E1 + E2 + E3; // 129024
constexpr int LOCN = 32 * N0;           // 524288

// ---- workspace layout (float offsets) ----
constexpr size_t O_XLZ  = 0;
constexpr size_t O_STAT = 128;      // 6 slots x 64 (sum|sumsq)
constexpr size_t O_XW0  = 512;      // 64x32 bcast
constexpr size_t O_YG0  = 2560;     // 256x32
constexpr size_t O_XG1  = 10752;
constexpr size_t O_XWG1 = 18944;
constexpr size_t O_YG1  = 27136;    // 1024x32
constexpr size_t O_XG2  = 59904;
constexpr size_t O_XWG2 = 92672;
constexpr size_t O_YG2  = 125440;   // 4096x32
constexpr size_t O_XG3  = 256512;
constexpr size_t O_XW3  = 387584;   // 4096x3
constexpr size_t O_YG3  = 399872;   // 16384x3
constexpr size_t O_DEG  = 449024;   // ints
constexpr size_t O_RP   = 470784;
constexpr size_t O_CUR  = 492548;
constexpr size_t O_EIDX = 514312;
constexpr size_t O_YL0  = 1169408;  // 16384x32
constexpr size_t O_XL1  = 1693696;
constexpr size_t O_YL1  = 2217984;
constexpr size_t O_XL2  = 2742272;
constexpr size_t O_YL2  = 3266560;
constexpr size_t O_XL3  = 3790848;
constexpr size_t O_YL3  = 4315136;  // 16384x3

struct Params {
    const float *z, *lin_w, *lin_b, *loc_w, *loc_b, *Wg, *bg, *Wg3, *bg3;
    const float *Wl, *bl, *Wl3, *bl3, *gam_g, *bet_g, *gam_l, *bet_l;
    const float *U0, *U1, *U2, *U3;
    const int *A0, *A1, *A2, *A3;
    float* ws;
    float* out;
};

// ================= K1: pre (zero deg/stats + linear head) =================
__global__ void __launch_bounds__(256) k_pre(Params P) {
    int t = threadIdx.x, b = blockIdx.x;
    float* ws = P.ws;
    if (b < 64) {
        int* deg = (int*)(ws + O_DEG);
        for (int i = b * 256 + t; i < 21760; i += 64 * 256) deg[i] = 0;
        if (b == 1) for (int i = t; i < 384; i += 256) (ws + O_STAT)[i] = 0.f;
        return;
    }
    __shared__ float zl[128];
    __shared__ float xl[160];
    __shared__ float xwl[32];
    if (t < 128) zl[t] = P.z[t];
    __syncthreads();
    if (t < 160) {
        float s = P.lin_b[t];
        for (int k = 0; k < 128; k++) s += zl[k] * P.lin_w[k * 160 + t];
        xl[t] = s;
    }
    __syncthreads();
    if (t < 128) (ws + O_XLZ)[t] = xl[32 + t];
    if (t < 32) {
        float s = 0.f;
        for (int k = 0; k < 32; k++) s += xl[k] * P.Wg[k * 32 + t];
        xwl[t] = s;
    }
    __syncthreads();
    for (int i = t; i < 2048; i += 256) (ws + O_XW0)[i] = xwl[i & 31];
}

// ================= K2: degree histogram (all graphs) =================
__global__ void __launch_bounds__(256) k_hist(Params P) {
    int* deg = (int*)(P.ws + O_DEG);
    for (int e = blockIdx.x * 256 + threadIdx.x; e < ETOT; e += 64 * 256) {
        const int* A; int E, dofs; int x = e;
        if (x < E0)              { A = P.A0; E = E0; dofs = 0; }
        else if ((x -= E0) < E1) { A = P.A1; E = E1; dofs = 16384; }
        else if ((x -= E1) < E2) { A = P.A2; E = E2; dofs = 20480; }
        else { x -= E2;            A = P.A3; E = E3; dofs = 21504; }
        atomicAdd(deg + dofs + A[E + x], 1);
    }
}

// ============ device: fused matvec + @Wl0 (one 1024-output chunk) ============
__device__ void matvec_y(const Params& P, int mb, float* sm) {
    float* xs = sm;          // 128
    float* xrow = sm + 128;  // 1024
    float* Wl = sm + 1152;   // 1024
    int t = threadIdx.x;
    if (t < 128) xs[t] = (P.ws + O_XLZ)[t];
    for (int i = t; i < 1024; i += 256) Wl[i] = P.Wl[i];
    __syncthreads();
    size_t j0 = (size_t)mb * 1024 + t * 4;
    float4 acc = *(const float4*)(P.loc_b + j0);
#pragma unroll 8
    for (int k = 0; k < 128; k++) {
        float xk = xs[k];
        float4 w = *(const float4*)(P.loc_w + (size_t)k * LOCN + j0);
        acc.x += xk * w.x; acc.y += xk * w.y; acc.z += xk * w.z; acc.w += xk * w.w;
    }
    *(float4*)(xrow + t * 4) = acc;
    __syncthreads();
    float* yl0 = P.ws + O_YL0;
#pragma unroll
    for (int q = 0; q < 4; q++) {
        int idx = q * 256 + t;
        int nn = idx >> 5, f = idx & 31;
        float s = 0.f;
        const float* xr = xrow + nn * 32;
#pragma unroll
        for (int k = 0; k < 32; k++) s += xr[k] * Wl[k * 32 + f];
        yl0[(size_t)mb * 1024 + idx] = s;
    }
}

// ================= K3: scan | U3 gemm | matvec[0:256] =================
__global__ void __launch_bounds__(256) k_l3(Params P) {
    __shared__ float sm[2304];
    int t = threadIdx.x, bid = blockIdx.x;
    float* ws = P.ws;
    if (bid < 4) {
        int n   = bid == 0 ? N0 : bid == 1 ? N1 : bid == 2 ? N2 : N3;
        int db  = bid == 0 ? 0 : bid == 1 ? 16384 : bid == 2 ? 20480 : 21504;
        int rbo = bid == 0 ? 0 : bid == 1 ? 16385 : bid == 2 ? 20482 : 21507;
        int per = n >> 8;
        const int* d = (int*)(ws + O_DEG) + db;
        int* rpp = (int*)(ws + O_RP) + rbo;
        int* cup = (int*)(ws + O_CUR) + rbo;
        int s = 0;
        for (int i = 0; i < per; i++) s += d[t * per + i];
        int* part = (int*)sm;
        part[t] = s;
        __syncthreads();
        for (int off = 1; off < 256; off <<= 1) {
            int v = (t >= off) ? part[t - off] : 0;
            __syncthreads();
            part[t] += v;
            __syncthreads();
        }
        int run = t ? part[t - 1] : 0;
        for (int i = 0; i < per; i++) {
            int idx = t * per + i;
            rpp[idx] = run; cup[idx] = run;
            run += d[idx];
        }
        if (t == 255) rpp[n] = part[255];
    } else if (bid == 4) {
        for (int i = t; i < 2048; i += 256) sm[i] = (ws + O_XW0)[i];
        __syncthreads();
        float acc[32];
#pragma unroll
        for (int f = 0; f < 32; f++) acc[f] = 0.f;
        for (int k = 0; k < 64; k++) {
            float u = P.U3[t * 64 + k];
#pragma unroll
            for (int f = 0; f < 32; f++) acc[f] += u * sm[k * 32 + f];
        }
        float* yp = ws + O_YG0 + t * 32;
#pragma unroll
        for (int f = 0; f < 32; f++) yp[f] = acc[f];
    } else {
        matvec_y(P, bid - 5, sm);
    }
}

// ================= K4: CSR fill | matvec[256:512] =================
__global__ void __launch_bounds__(256) k_l4(Params P) {
    __shared__ float sm[2304];
    int t = threadIdx.x, bid = blockIdx.x;
    float* ws = P.ws;
    if (bid < 64) {
        int* cur  = (int*)(ws + O_CUR);
        int* eidx = (int*)(ws + O_EIDX);
        for (int e = bid * 256 + t; e < ETOT; e += 64 * 256) {
            const int* A; int E, cofs, eofs; int x = e;
            if (x < E0)              { A = P.A0; E = E0; cofs = 0;     eofs = 0; }
            else if ((x -= E0) < E1) { A = P.A1; E = E1; cofs = 16385; eofs = 98304; }
            else if ((x -= E1) < E2) { A = P.A2; E = E2; cofs = 20482; eofs = 122880; }
            else { x -= E2;            A = P.A3; E = E3; cofs = 21507; eofs = 129024; }
            int srcn = A[x], dd = A[E + x];
            int slot = atomicAdd(cur + cofs + dd, 1);
            eidx[eofs + slot] = srcn;
        }
    } else {
        matvec_y(P, bid - 64 + 256, sm);
    }
}

// ============ device: pull gather (F=32) + bias + BN stats ============
// grid-stride, one wave per node per step; register-accumulated stats,
// LDS block-reduce, one global atomic per feature per block.
__device__ void gatherG(const int* rp, const int* ei, const float* y,
                        const float* bias, int n, float* xout, float* stats,
                        int rb, int nrb, float* sm) {
    int t = threadIdx.x, f = t & 31, half = (t >> 5) & 1, w = t >> 6;
    float bf = bias[f];
    float s = 0.f, ss = 0.f;
    for (int node = rb * 8 + w; node < n; node += nrb * 8) {
        int r0 = rp[node], r1 = rp[node + 1];
        float a = half ? 0.f : y[(size_t)node * 32 + f];
        for (int r = r0 + half; r < r1; r += 2)
            a += y[(size_t)ei[r] * 32 + f];
        a += __shfl_down(a, 32, 64);
        if (!half) {
            float v = a / (float)(r1 - r0 + 1) + bf;
            xout[(size_t)node * 32 + f] = v;
            s += v; ss += v * v;
        }
    }
    if (t < 64) sm[t] = 0.f;
    __syncthreads();
    if (!half) { atomicAdd(sm + f, s); atomicAdd(sm + 32 + f, ss); }
    __syncthreads();
    if (t < 64) atomicAdd(stats + t, sm[t]);
}

// ============ device: BN + leakyReLU + row @ W(32xFO), 512 threads ============
template <int FO>
__device__ void bnxw512(const float* xin, const float* stats, const float* gam,
                        const float* bet, const float* W, float invn, int n,
                        float* out, int rb, float* sm) {
    float* Wl = sm;
    float* sc = sm + 32 * FO;
    float* sh = sc + 32;
    int t = threadIdx.x;
    for (int i = t; i < 32 * FO; i += 512) Wl[i] = W[i];
    if (t < 32) {
        float mu = stats[t] * invn;
        float var = stats[32 + t] * invn - mu * mu;
        float rs = rsqrtf(var + 1e-5f);
        float scv = rs * gam[t];
        sc[t] = scv; sh[t] = bet[t] - mu * scv;
    }
    __syncthreads();
    int node = rb * 512 + t;
    if (node < n) {
        float x[32];
        const float4* xp = (const float4*)(xin + (size_t)node * 32);
#pragma unroll
        for (int j = 0; j < 8; j++) {
            float4 v = xp[j];
            x[4 * j] = v.x; x[4 * j + 1] = v.y; x[4 * j + 2] = v.z; x[4 * j + 3] = v.w;
        }
#pragma unroll
        for (int k = 0; k < 32; k++) {
            float v = sc[k] * x[k] + sh[k];
            x[k] = v > 0.f ? v : 0.01f * v;
        }
        float yv[FO];
#pragma unroll
        for (int q = 0; q < FO; q++) {
            float s = 0.f;
#pragma unroll
            for (int k = 0; k < 32; k++) s += x[k] * Wl[k * FO + q];
            yv[q] = s;
        }
        float* yp = out + (size_t)node * FO;
#pragma unroll
        for (int q = 0; q < FO; q++) yp[q] = yv[q];
    }
}

// ============ device: y = U(64 rows) @ xw(m x 32), 512 threads ============
__device__ void gemm512(const float* U, const float* xw, int m, float* y,
                        int rb, float* sm) {
    float* ut = sm;          // 64*64
    float* xt = sm + 4096;   // 64*32
    int t = threadIdx.x, f = t & 31, rg = t >> 5; // rg 0..15
    int r0 = rb * 64;
    float a0 = 0, a1 = 0, a2 = 0, a3 = 0;
    for (int k0 = 0; k0 < m; k0 += 64) {
        {
            int row = t >> 3, c0 = (t & 7) * 8;
            const float* src = U + (size_t)(r0 + row) * m + k0 + c0;
            *(float4*)(ut + row * 64 + c0) = *(const float4*)src;
            *(float4*)(ut + row * 64 + c0 + 4) = *(const float4*)(src + 4);
        }
        {
            int kk = t >> 3, c0 = (t & 7) * 4;
            *(float4*)(xt + kk * 32 + c0) =
                *(const float4*)(xw + (size_t)(k0 + kk) * 32 + c0);
        }
        __syncthreads();
#pragma unroll
        for (int kk = 0; kk < 64; kk++) {
            float xv = xt[kk * 32 + f];
            a0 += ut[rg * 64 + kk] * xv;
            a1 += ut[(rg + 16) * 64 + kk] * xv;
            a2 += ut[(rg + 32) * 64 + kk] * xv;
            a3 += ut[(rg + 48) * 64 + kk] * xv;
        }
        __syncthreads();
    }
    y[(size_t)(r0 + rg) * 32 + f] = a0;
    y[(size_t)(r0 + rg + 16) * 32 + f] = a1;
    y[(size_t)(r0 + rg + 32) * 32 + f] = a2;
    y[(size_t)(r0 + rg + 48) * 32 + f] = a3;
}

// ================= K5: gather_l0 | gather_g0 =================
__global__ void __launch_bounds__(512) k_l5(Params P) {
    __shared__ float sm[64];
    int bid = blockIdx.x;
    float* ws = P.ws;
    const int* rp = (int*)(ws + O_RP);
    const int* ei = (int*)(ws + O_EIDX);
    if (bid < 512)
        gatherG(rp, ei, ws + O_YL0, P.bl, N0, ws + O_XL1, ws + O_STAT + 192,
                bid, 512, sm);
    else
        gatherG(rp + 21507, ei + 129024, ws + O_YG0, P.bg, N3, ws + O_XG1,
                ws + O_STAT, bid - 512, 8, sm);
}

// ================= K6: bnxw_l0 | bnxw_g0 =================
__global__ void __launch_bounds__(512) k_l6(Params P) {
    __shared__ float sm[1152];
    int bid = blockIdx.x;
    float* ws = P.ws;
    if (bid < 32)
        bnxw512<32>(ws + O_XL1, ws + O_STAT + 192, P.gam_l, P.bet_l, P.Wl + 1024,
                    1.f / N0, N0, ws + O_YL1, bid, sm);
    else
        bnxw512<32>(ws + O_XG1, ws + O_STAT, P.gam_g, P.bet_g, P.Wg + 1024,
                    1.f / N3, N3, ws + O_XWG1, bid - 32, sm);
}

// ================= K7: gather_l1 | gemm_g1 (U2) =================
__global__ void __launch_bounds__(512) k_l7(Params P) {
    __shared__ float sm[6144];
    int bid = blockIdx.x;
    float* ws = P.ws;
    const int* rp = (int*)(ws + O_RP);
    const int* ei = (int*)(ws + O_EIDX);
    if (bid < 512)
        gatherG(rp, ei, ws + O_YL1, P.bl + 32, N0, ws + O_XL2,
                ws + O_STAT + 256, bid, 512, sm);
    else
        gemm512(P.U2, ws + O_XWG1, 256, ws + O_YG1, bid - 512, sm);
}

// ================= K8: bnxw_l1 | gather_g1 =================
__global__ void __launch_bounds__(512) k_l8(Params P) {
    __shared__ float sm[1152];
    int bid = blockIdx.x;
    float* ws = P.ws;
    const int* rp = (int*)(ws + O_RP);
    const int* ei = (int*)(ws + O_EIDX);
    if (bid < 32)
        bnxw512<32>(ws + O_XL2, ws + O_STAT + 256, P.gam_l + 32, P.bet_l + 32,
                    P.Wl + 2048, 1.f / N0, N0, ws + O_YL2, bid, sm);
    else
        gatherG(rp + 20482, ei + 122880, ws + O_YG1, P.bg + 32, N2,
                ws + O_XG2, ws + O_STAT + 64, bid - 32, 16, sm);
}

// ================= K9: gather_l2 | bnxw_g1 =================
__global__ void __launch_bounds__(512) k_l9(Params P) {
    __shared__ float sm[1152];
    int bid = blockIdx.x;
    float* ws = P.ws;
    const int* rp = (int*)(ws + O_RP);
    const int* ei = (int*)(ws + O_EIDX);
    if (bid < 512)
        gatherG(rp, ei, ws + O_YL2, P.bl + 64, N0, ws + O_XL3,
                ws + O_STAT + 320, bid, 512, sm);
    else
        bnxw512<32>(ws + O_XG2, ws + O_STAT + 64, P.gam_g + 32, P.bet_g + 32,
                    P.Wg + 2048, 1.f / N2, N2, ws + O_XWG2, bid - 512, sm);
}

// ================= K10: bnxw_l2 (FO=3) | gemm_g2 (U1) =================
__global__ void __launch_bounds__(512) k_l10(Params P) {
    __shared__ float sm[6144];
    int bid = blockIdx.x;
    float* ws = P.ws;
    if (bid < 32)
        bnxw512<3>(ws + O_XL3, ws + O_STAT + 320, P.gam_l + 64, P.bet_l + 64,
                   P.Wl3, 1.f / N0, N0, ws + O_YL3, bid, sm);
    else
        gemm512(P.U1, ws + O_XWG2, 1024, ws + O_YG2, bid - 32, sm);
}

// ================= K11: gather_g2 =================
__global__ void __launch_bounds__(512) k_l11(Params P) {
    __shared__ float sm[64];
    float* ws = P.ws;
    const int* rp = (int*)(ws + O_RP);
    const int* ei = (int*)(ws + O_EIDX);
    gatherG(rp + 16385, ei + 98304, ws + O_YG2, P.bg + 64, N1,
            ws + O_XG3, ws + O_STAT + 128, blockIdx.x, 64, sm);
}

// ================= K12: bnxw_g2 (FO=3) =================
__global__ void __launch_bounds__(512) k_l12(Params P) {
    __shared__ float sm[256];
    bnxw512<3>(P.ws + O_XG3, P.ws + O_STAT + 128, P.gam_g + 64, P.bet_g + 64,
               P.Wg3, 1.f / N1, N1, P.ws + O_XW3, blockIdx.x, sm);
}

// ================= K13: yg3 = U0 @ xw3 (268 MB stream) =================
__global__ void __launch_bounds__(256) k_gemmU3(Params P) {
    __shared__ float pl[3 * 4096];
    int t = threadIdx.x;
    const float* xw3 = P.ws + O_XW3;
    float* y = P.ws + O_YG3;
    for (int i = t; i < 12288; i += 256) {
        int k = i / 3, h = i - 3 * k;
        pl[h * 4096 + ((k & 3) << 10) + (k >> 2)] = xw3[i];
    }
    __syncthreads();
    int w = t >> 6, lane = t & 63;
    for (int rr = 0; rr < 4; rr++) {
        int row = blockIdx.x * 16 + w * 4 + rr;
        const float4* up = (const float4*)(P.U0 + (size_t)row * 4096);
        float a0 = 0, a1 = 0, a2 = 0;
#pragma unroll 4
        for (int c = 0; c < 16; c++) {
            float4 u = up[c * 64 + lane];
            int b = c * 64 + lane;
            a0 += u.x * pl[b]        + u.y * pl[1024 + b]  + u.z * pl[2048 + b]   + u.w * pl[3072 + b];
            a1 += u.x * pl[4096 + b] + u.y * pl[5120 + b]  + u.z * pl[6144 + b]   + u.w * pl[7168 + b];
            a2 += u.x * pl[8192 + b] + u.y * pl[9216 + b]  + u.z * pl[10240 + b]  + u.w * pl[11264 + b];
        }
        for (int o = 32; o; o >>= 1) {
            a0 += __shfl_down(a0, o, 64);
            a1 += __shfl_down(a1, o, 64);
            a2 += __shfl_down(a2, o, 64);
        }
        if (lane == 0) { y[row * 3] = a0; y[row * 3 + 1] = a1; y[row * 3 + 2] = a2; }
    }
}

// ================= K14: final combine over A0 =================
__global__ void __launch_bounds__(256) k_final(Params P) {
    int t = blockIdx.x * 256 + threadIdx.x;
    int node = t >> 2, r = t & 3;
    if (node >= N0 || r >= 3) return;
    float* ws = P.ws;
    const int* rp = (int*)(ws + O_RP);
    const int* ei = (int*)(ws + O_EIDX);
    const float* yg = ws + O_YG3;
    const float* yl = ws + O_YL3;
    int r0 = rp[node], r1 = rp[node + 1];
    float ag = yg[node * 3 + r], al = yl[node * 3 + r];
    int e = r0;
    for (; e + 4 <= r1; e += 4) {
        int s0 = ei[e], s1 = ei[e + 1], s2 = ei[e + 2], s3 = ei[e + 3];
        ag += yg[s0 * 3 + r] + yg[s1 * 3 + r] + yg[s2 * 3 + r] + yg[s3 * 3 + r];
        al += yl[s0 * 3 + r] + yl[s1 * 3 + r] + yl[s2 * 3 + r] + yl[s3 * 3 + r];
    }
    for (; e < r1; e++) { ag += yg[ei[e] * 3 + r]; al += yl[ei[e] * 3 + r]; }
    float inv = 1.f / (float)(r1 - r0 + 1);
    P.out[node * 3 + r] = 0.01f * (ag * inv + P.bg3[r]) + 0.99f * (al * inv + P.bl3[r]);
}

extern "C" void kernel_launch(void* const* d_in, const int* in_sizes, int n_in,
                              void* d_out, int out_size, void* d_ws, size_t ws_size,
                              hipStream_t stream) {
    Params p;
    p.z     = (const float*)d_in[0];
    p.lin_w = (const float*)d_in[1];
    p.lin_b = (const float*)d_in[2];
    p.loc_w = (const float*)d_in[3];
    p.loc_b = (const float*)d_in[4];
    p.Wg    = (const float*)d_in[5];
    p.bg    = (const float*)d_in[8];
    p.Wg3   = (const float*)d_in[9];
    p.bg3   = (const float*)d_in[12];
    p.Wl    = (const float*)d_in[13];
    p.bl    = (const float*)d_in[16];
    p.Wl3   = (const float*)d_in[17];
    p.bl3   = (const float*)d_in[20];
    p.gam_g = (const float*)d_in[21];
    p.bet_g = (const float*)d_in[22];
    p.gam_l = (const float*)d_in[23];
    p.bet_l = (const float*)d_in[24];
    p.U0    = (const float*)d_in[25];
    p.U1    = (const float*)d_in[26];
    p.U2    = (const float*)d_in[27];
    p.U3    = (const float*)d_in[28];
    p.A0    = (const int*)d_in[29];
    p.A1    = (const int*)d_in[30];
    p.A2    = (const int*)d_in[31];
    p.A3    = (const int*)d_in[32];
    p.ws    = (float*)d_ws;
    p.out   = (float*)d_out;

    k_pre   <<<65,   256, 0, stream>>>(p);
    k_hist  <<<64,   256, 0, stream>>>(p);
    k_l3    <<<261,  256, 0, stream>>>(p);  // scan | U3 gemm | matvec 0:256
    k_l4    <<<320,  256, 0, stream>>>(p);  // fill | matvec 256:512
    k_l5    <<<520,  512, 0, stream>>>(p);  // gather_l0 | gather_g0
    k_l6    <<<33,   512, 0, stream>>>(p);  // bnxw_l0 | bnxw_g0
    k_l7    <<<528,  512, 0, stream>>>(p);  // gather_l1 | gemm_g1
    k_l8    <<<48,   512, 0, stream>>>(p);  // bnxw_l1 | gather_g1
    k_l9    <<<514,  512, 0, stream>>>(p);  // gather_l2 | bnxw_g1
    k_l10   <<<96,   512, 0, stream>>>(p);  // bnxw_l2 | gemm_g2
    k_l11   <<<64,   512, 0, stream>>>(p);  // gather_g2
    k_l12   <<<8,    512, 0, stream>>>(p);  // bnxw_g2
    k_gemmU3<<<1024, 256, 0, stream>>>(p);  // U0 @ xw3
    k_final <<<256,  256, 0, stream>>>(p);  // combine
}

// Round 10
// 378.556 us; speedup vs baseline: 3.8591x; 1.1553x over previous
//
#include <hip/hip_runtime.h>
#include <cstddef>

constexpr int N0 = 16384, N1 = 4096, N2 = 1024, N3 = 256;
constexpr int E0 = 6 * N0, E1 = 6 * N1, E2 = 6 * N2, E3 = 6 * N3;
constexpr int ETOT = E0 + E1 + E2 + E3; // 129024
constexpr int LOCN = 32 * N0;           // 524288

// ---- workspace layout (float offsets) ----
constexpr size_t O_XLZ  = 0;
constexpr size_t O_STAT = 128;      // 6 slots x 64 (sum|sumsq)
constexpr size_t O_XW0  = 512;      // 64x32 bcast
constexpr size_t O_YG0  = 2560;     // 256x32
constexpr size_t O_XG1  = 10752;
constexpr size_t O_XWG1 = 18944;
constexpr size_t O_YG1  = 27136;    // 1024x32
constexpr size_t O_XG2  = 59904;
constexpr size_t O_XWG2 = 92672;
constexpr size_t O_YG2  = 125440;   // 4096x32
constexpr size_t O_XG3  = 256512;
constexpr size_t O_XW3  = 387584;   // 4096x3
constexpr size_t O_YG3  = 399872;   // 16384x3
constexpr size_t O_DEG  = 449024;   // ints
constexpr size_t O_RP   = 470784;
constexpr size_t O_CUR  = 492548;
constexpr size_t O_EIDX = 514312;
constexpr size_t O_YL0  = 1169408;  // 16384x32
constexpr size_t O_XL1  = 1693696;
constexpr size_t O_YL1  = 2217984;
constexpr size_t O_XL2  = 2742272;
constexpr size_t O_YL2  = 3266560;
constexpr size_t O_XL3  = 3790848;
constexpr size_t O_YL3  = 4315136;  // 16384x3

struct Params {
    const float *z, *lin_w, *lin_b, *loc_w, *loc_b, *Wg, *bg, *Wg3, *bg3;
    const float *Wl, *bl, *Wl3, *bl3, *gam_g, *bet_g, *gam_l, *bet_l;
    const float *U0, *U1, *U2, *U3;
    const int *A0, *A1, *A2, *A3;
    float* ws;
    float* out;
};

// ================= K1: pre (zero deg/stats + linear head) =================
__global__ void __launch_bounds__(256) k_pre(Params P) {
    int t = threadIdx.x, b = blockIdx.x;
    float* ws = P.ws;
    if (b < 64) {
        int* deg = (int*)(ws + O_DEG);
        for (int i = b * 256 + t; i < 21760; i += 64 * 256) deg[i] = 0;
        if (b == 1) for (int i = t; i < 384; i += 256) (ws + O_STAT)[i] = 0.f;
        return;
    }
    __shared__ float zl[128];
    __shared__ float xl[160];
    __shared__ float xwl[32];
    if (t < 128) zl[t] = P.z[t];
    __syncthreads();
    if (t < 160) {
        float s = P.lin_b[t];
        for (int k = 0; k < 128; k++) s += zl[k] * P.lin_w[k * 160 + t];
        xl[t] = s;
    }
    __syncthreads();
    if (t < 128) (ws + O_XLZ)[t] = xl[32 + t];
    if (t < 32) {
        float s = 0.f;
        for (int k = 0; k < 32; k++) s += xl[k] * P.Wg[k * 32 + t];
        xwl[t] = s;
    }
    __syncthreads();
    for (int i = t; i < 2048; i += 256) (ws + O_XW0)[i] = xwl[i & 31];
}

// ============ device: fused matvec + @Wl0 (one 1024-output chunk) ============
__device__ void matvec_y(const Params& P, int mb, float* sm) {
    float* xs = sm;          // 128
    float* xrow = sm + 128;  // 1024
    float* Wl = sm + 1152;   // 1024
    int t = threadIdx.x;
    if (t < 128) xs[t] = (P.ws + O_XLZ)[t];
    for (int i = t; i < 1024; i += 256) Wl[i] = P.Wl[i];
    __syncthreads();
    size_t j0 = (size_t)mb * 1024 + t * 4;
    float4 acc = *(const float4*)(P.loc_b + j0);
#pragma unroll 8
    for (int k = 0; k < 128; k++) {
        float xk = xs[k];
        float4 w = *(const float4*)(P.loc_w + (size_t)k * LOCN + j0);
        acc.x += xk * w.x; acc.y += xk * w.y; acc.z += xk * w.z; acc.w += xk * w.w;
    }
    *(float4*)(xrow + t * 4) = acc;
    __syncthreads();
    float* yl0 = P.ws + O_YL0;
#pragma unroll
    for (int q = 0; q < 4; q++) {
        int idx = q * 256 + t;
        int nn = idx >> 5, f = idx & 31;
        float s = 0.f;
        const float* xr = xrow + nn * 32;
#pragma unroll
        for (int k = 0; k < 32; k++) s += xr[k] * Wl[k * 32 + f];
        yl0[(size_t)mb * 1024 + idx] = s;
    }
}

// ================= K2: matvec[0:191) | hist | U3 gemm  (256 blocks) =================
__global__ void __launch_bounds__(256) k_l2(Params P) {
    __shared__ float sm[2304];
    int t = threadIdx.x, bid = blockIdx.x;
    float* ws = P.ws;
    if (bid < 191) {
        matvec_y(P, bid, sm);
    } else if (bid < 255) {
        int* deg = (int*)(ws + O_DEG);
        for (int e = (bid - 191) * 256 + t; e < ETOT; e += 64 * 256) {
            const int* A; int E, dofs; int x = e;
            if (x < E0)              { A = P.A0; E = E0; dofs = 0; }
            else if ((x -= E0) < E1) { A = P.A1; E = E1; dofs = 16384; }
            else if ((x -= E1) < E2) { A = P.A2; E = E2; dofs = 20480; }
            else { x -= E2;            A = P.A3; E = E3; dofs = 21504; }
            atomicAdd(deg + dofs + A[E + x], 1);
        }
    } else {
        for (int i = t; i < 2048; i += 256) sm[i] = (ws + O_XW0)[i];
        __syncthreads();
        float acc[32];
#pragma unroll
        for (int f = 0; f < 32; f++) acc[f] = 0.f;
        for (int k = 0; k < 64; k++) {
            float u = P.U3[t * 64 + k];
#pragma unroll
            for (int f = 0; f < 32; f++) acc[f] += u * sm[k * 32 + f];
        }
        float* yp = ws + O_YG0 + t * 32;
#pragma unroll
        for (int f = 0; f < 32; f++) yp[f] = acc[f];
    }
}

// ================= K3: matvec[191:443) | scan  (256 blocks) =================
__global__ void __launch_bounds__(256) k_l3(Params P) {
    __shared__ float sm[2304];
    int t = threadIdx.x, bid = blockIdx.x;
    float* ws = P.ws;
    if (bid < 252) {
        matvec_y(P, 191 + bid, sm);
    } else {
        int g = bid - 252;
        int n   = g == 0 ? N0 : g == 1 ? N1 : g == 2 ? N2 : N3;
        int db  = g == 0 ? 0 : g == 1 ? 16384 : g == 2 ? 20480 : 21504;
        int rbo = g == 0 ? 0 : g == 1 ? 16385 : g == 2 ? 20482 : 21507;
        int per = n >> 8;
        const int* d = (int*)(ws + O_DEG) + db;
        int* rpp = (int*)(ws + O_RP) + rbo;
        int* cup = (int*)(ws + O_CUR) + rbo;
        int s = 0;
        for (int i = 0; i < per; i++) s += d[t * per + i];
        int* part = (int*)sm;
        part[t] = s;
        __syncthreads();
        for (int off = 1; off < 256; off <<= 1) {
            int v = (t >= off) ? part[t - off] : 0;
            __syncthreads();
            part[t] += v;
            __syncthreads();
        }
        int run = t ? part[t - 1] : 0;
        for (int i = 0; i < per; i++) {
            int idx = t * per + i;
            rpp[idx] = run; cup[idx] = run;
            run += d[idx];
        }
        if (t == 255) rpp[n] = part[255];
    }
}

// ================= K4: matvec[443:512) | CSR fill  (133 blocks) =================
__global__ void __launch_bounds__(256) k_l4(Params P) {
    __shared__ float sm[2304];
    int t = threadIdx.x, bid = blockIdx.x;
    float* ws = P.ws;
    if (bid < 69) {
        matvec_y(P, 443 + bid, sm);
    } else {
        int* cur  = (int*)(ws + O_CUR);
        int* eidx = (int*)(ws + O_EIDX);
        for (int e = (bid - 69) * 256 + t; e < ETOT; e += 64 * 256) {
            const int* A; int E, cofs, eofs; int x = e;
            if (x < E0)              { A = P.A0; E = E0; cofs = 0;     eofs = 0; }
            else if ((x -= E0) < E1) { A = P.A1; E = E1; cofs = 16385; eofs = 98304; }
            else if ((x -= E1) < E2) { A = P.A2; E = E2; cofs = 20482; eofs = 122880; }
            else { x -= E2;            A = P.A3; E = E3; cofs = 21507; eofs = 129024; }
            int srcn = A[x], dd = A[E + x];
            int slot = atomicAdd(cur + cofs + dd, 1);
            eidx[eofs + slot] = srcn;
        }
    }
}

// ============ device: pull gather (F=32) + bias + BN stats ============
__device__ void gatherG(const int* rp, const int* ei, const float* y,
                        const float* bias, int n, float* xout, float* stats,
                        int rb, int nrb, float* sm) {
    int t = threadIdx.x, f = t & 31, half = (t >> 5) & 1, w = t >> 6;
    float bf = bias[f];
    float s = 0.f, ss = 0.f;
    for (int node = rb * 8 + w; node < n; node += nrb * 8) {
        int r0 = rp[node], r1 = rp[node + 1];
        float a = half ? 0.f : y[(size_t)node * 32 + f];
        for (int r = r0 + half; r < r1; r += 2)
            a += y[(size_t)ei[r] * 32 + f];
        a += __shfl_down(a, 32, 64);
        if (!half) {
            float v = a / (float)(r1 - r0 + 1) + bf;
            xout[(size_t)node * 32 + f] = v;
            s += v; ss += v * v;
        }
    }
    if (t < 64) sm[t] = 0.f;
    __syncthreads();
    if (!half) { atomicAdd(sm + f, s); atomicAdd(sm + 32 + f, ss); }
    __syncthreads();
    if (t < 64) atomicAdd(stats + t, sm[t]);
}

// ============ device: BN + leakyReLU + row @ W(32xFO), 512 threads ============
template <int FO>
__device__ void bnxw512(const float* xin, const float* stats, const float* gam,
                        const float* bet, const float* W, float invn, int n,
                        float* out, int rb, float* sm) {
    float* Wl = sm;
    float* sc = sm + 32 * FO;
    float* sh = sc + 32;
    int t = threadIdx.x;
    for (int i = t; i < 32 * FO; i += 512) Wl[i] = W[i];
    if (t < 32) {
        float mu = stats[t] * invn;
        float var = stats[32 + t] * invn - mu * mu;
        float rs = rsqrtf(var + 1e-5f);
        float scv = rs * gam[t];
        sc[t] = scv; sh[t] = bet[t] - mu * scv;
    }
    __syncthreads();
    int node = rb * 512 + t;
    if (node < n) {
        float x[32];
        const float4* xp = (const float4*)(xin + (size_t)node * 32);
#pragma unroll
        for (int j = 0; j < 8; j++) {
            float4 v = xp[j];
            x[4 * j] = v.x; x[4 * j + 1] = v.y; x[4 * j + 2] = v.z; x[4 * j + 3] = v.w;
        }
#pragma unroll
        for (int k = 0; k < 32; k++) {
            float v = sc[k] * x[k] + sh[k];
            x[k] = v > 0.f ? v : 0.01f * v;
        }
        float yv[FO];
#pragma unroll
        for (int q = 0; q < FO; q++) {
            float s = 0.f;
#pragma unroll
            for (int k = 0; k < 32; k++) s += x[k] * Wl[k * FO + q];
            yv[q] = s;
        }
        float* yp = out + (size_t)node * FO;
#pragma unroll
        for (int q = 0; q < FO; q++) yp[q] = yv[q];
    }
}

// ============ device: y = U(64 rows) @ xw(m x 32), 512 threads ============
__device__ void gemm512(const float* U, const float* xw, int m, float* y,
                        int rb, float* sm) {
    float* ut = sm;          // 64*64
    float* xt = sm + 4096;   // 64*32
    int t = threadIdx.x, f = t & 31, rg = t >> 5; // rg 0..15
    int r0 = rb * 64;
    float a0 = 0, a1 = 0, a2 = 0, a3 = 0;
    for (int k0 = 0; k0 < m; k0 += 64) {
        {
            int row = t >> 3, c0 = (t & 7) * 8;
            const float* src = U + (size_t)(r0 + row) * m + k0 + c0;
            *(float4*)(ut + row * 64 + c0) = *(const float4*)src;
            *(float4*)(ut + row * 64 + c0 + 4) = *(const float4*)(src + 4);
        }
        {
            int kk = t >> 3, c0 = (t & 7) * 4;
            *(float4*)(xt + kk * 32 + c0) =
                *(const float4*)(xw + (size_t)(k0 + kk) * 32 + c0);
        }
        __syncthreads();
#pragma unroll
        for (int kk = 0; kk < 64; kk++) {
            float xv = xt[kk * 32 + f];
            a0 += ut[rg * 64 + kk] * xv;
            a1 += ut[(rg + 16) * 64 + kk] * xv;
            a2 += ut[(rg + 32) * 64 + kk] * xv;
            a3 += ut[(rg + 48) * 64 + kk] * xv;
        }
        __syncthreads();
    }
    y[(size_t)(r0 + rg) * 32 + f] = a0;
    y[(size_t)(r0 + rg + 16) * 32 + f] = a1;
    y[(size_t)(r0 + rg + 32) * 32 + f] = a2;
    y[(size_t)(r0 + rg + 48) * 32 + f] = a3;
}

// ================= K5: gather_l0 | gather_g0  (256 blocks) =================
__global__ void __launch_bounds__(512) k_l5(Params P) {
    __shared__ float sm[64];
    int bid = blockIdx.x;
    float* ws = P.ws;
    const int* rp = (int*)(ws + O_RP);
    const int* ei = (int*)(ws + O_EIDX);
    if (bid < 240)
        gatherG(rp, ei, ws + O_YL0, P.bl, N0, ws + O_XL1, ws + O_STAT + 192,
                bid, 240, sm);
    else
        gatherG(rp + 21507, ei + 129024, ws + O_YG0, P.bg, N3, ws + O_XG1,
                ws + O_STAT, bid - 240, 16, sm);
}

// ================= K6: bnxw_l0 | bnxw_g0  (33 blocks) =================
__global__ void __launch_bounds__(512) k_l6(Params P) {
    __shared__ float sm[1152];
    int bid = blockIdx.x;
    float* ws = P.ws;
    if (bid < 32)
        bnxw512<32>(ws + O_XL1, ws + O_STAT + 192, P.gam_l, P.bet_l, P.Wl + 1024,
                    1.f / N0, N0, ws + O_YL1, bid, sm);
    else
        bnxw512<32>(ws + O_XG1, ws + O_STAT, P.gam_g, P.bet_g, P.Wg + 1024,
                    1.f / N3, N3, ws + O_XWG1, bid - 32, sm);
}

// ================= K7: gather_l1 | gemm_g1 (U2)  (256 blocks) =================
__global__ void __launch_bounds__(512) k_l7(Params P) {
    __shared__ float sm[6144];
    int bid = blockIdx.x;
    float* ws = P.ws;
    const int* rp = (int*)(ws + O_RP);
    const int* ei = (int*)(ws + O_EIDX);
    if (bid < 240)
        gatherG(rp, ei, ws + O_YL1, P.bl + 32, N0, ws + O_XL2,
                ws + O_STAT + 256, bid, 240, sm);
    else
        gemm512(P.U2, ws + O_XWG1, 256, ws + O_YG1, bid - 240, sm);
}

// ================= K8: bnxw_l1 | gather_g1  (48 blocks) =================
__global__ void __launch_bounds__(512) k_l8(Params P) {
    __shared__ float sm[1152];
    int bid = blockIdx.x;
    float* ws = P.ws;
    const int* rp = (int*)(ws + O_RP);
    const int* ei = (int*)(ws + O_EIDX);
    if (bid < 32)
        bnxw512<32>(ws + O_XL2, ws + O_STAT + 256, P.gam_l + 32, P.bet_l + 32,
                    P.Wl + 2048, 1.f / N0, N0, ws + O_YL2, bid, sm);
    else
        gatherG(rp + 20482, ei + 122880, ws + O_YG1, P.bg + 32, N2,
                ws + O_XG2, ws + O_STAT + 64, bid - 32, 16, sm);
}

// ================= K9: gather_l2 | bnxw_g1  (242 blocks) =================
__global__ void __launch_bounds__(512) k_l9(Params P) {
    __shared__ float sm[1152];
    int bid = blockIdx.x;
    float* ws = P.ws;
    const int* rp = (int*)(ws + O_RP);
    const int* ei = (int*)(ws + O_EIDX);
    if (bid < 240)
        gatherG(rp, ei, ws + O_YL2, P.bl + 64, N0, ws + O_XL3,
                ws + O_STAT + 320, bid, 240, sm);
    else
        bnxw512<32>(ws + O_XG2, ws + O_STAT + 64, P.gam_g + 32, P.bet_g + 32,
                    P.Wg + 2048, 1.f / N2, N2, ws + O_XWG2, bid - 240, sm);
}

// ================= K10: bnxw_l2 (FO=3) | gemm_g2 (U1)  (96 blocks) =================
__global__ void __launch_bounds__(512) k_l10(Params P) {
    __shared__ float sm[6144];
    int bid = blockIdx.x;
    float* ws = P.ws;
    if (bid < 32)
        bnxw512<3>(ws + O_XL3, ws + O_STAT + 320, P.gam_l + 64, P.bet_l + 64,
                   P.Wl3, 1.f / N0, N0, ws + O_YL3, bid, sm);
    else
        gemm512(P.U1, ws + O_XWG2, 1024, ws + O_YG2, bid - 32, sm);
}

// ================= K11: gather_g2  (64 blocks) =================
__global__ void __launch_bounds__(512) k_l11(Params P) {
    __shared__ float sm[64];
    float* ws = P.ws;
    const int* rp = (int*)(ws + O_RP);
    const int* ei = (int*)(ws + O_EIDX);
    gatherG(rp + 16385, ei + 98304, ws + O_YG2, P.bg + 64, N1,
            ws + O_XG3, ws + O_STAT + 128, blockIdx.x, 64, sm);
}

// ================= K12: bnxw_g2 (FO=3)  (8 blocks) =================
__global__ void __launch_bounds__(512) k_l12(Params P) {
    __shared__ float sm[256];
    bnxw512<3>(P.ws + O_XG3, P.ws + O_STAT + 128, P.gam_g + 64, P.bet_g + 64,
               P.Wg3, 1.f / N1, N1, P.ws + O_XW3, blockIdx.x, sm);
}

// ================= K13: yg3 = U0 @ xw3  (256 blocks, 64 rows each) =================
__global__ void __launch_bounds__(256) k_gemmU3(Params P) {
    __shared__ float pl[3 * 4096];
    int t = threadIdx.x;
    const float* xw3 = P.ws + O_XW3;
    float* y = P.ws + O_YG3;
    for (int i = t; i < 12288; i += 256) {
        int k = i / 3, h = i - 3 * k;
        pl[h * 4096 + ((k & 3) << 10) + (k >> 2)] = xw3[i];
    }
    __syncthreads();
    int w = t >> 6, lane = t & 63;
    for (int it = 0; it < 4; it++) {
        for (int rr = 0; rr < 4; rr++) {
            int row = it * 4096 + blockIdx.x * 16 + w * 4 + rr;
            const float4* up = (const float4*)(P.U0 + (size_t)row * 4096);
            float a0 = 0, a1 = 0, a2 = 0;
#pragma unroll 4
            for (int c = 0; c < 16; c++) {
                float4 u = up[c * 64 + lane];
                int b = c * 64 + lane;
                a0 += u.x * pl[b]        + u.y * pl[1024 + b]  + u.z * pl[2048 + b]   + u.w * pl[3072 + b];
                a1 += u.x * pl[4096 + b] + u.y * pl[5120 + b]  + u.z * pl[6144 + b]   + u.w * pl[7168 + b];
                a2 += u.x * pl[8192 + b] + u.y * pl[9216 + b]  + u.z * pl[10240 + b]  + u.w * pl[11264 + b];
            }
            for (int o = 32; o; o >>= 1) {
                a0 += __shfl_down(a0, o, 64);
                a1 += __shfl_down(a1, o, 64);
                a2 += __shfl_down(a2, o, 64);
            }
            if (lane == 0) { y[row * 3] = a0; y[row * 3 + 1] = a1; y[row * 3 + 2] = a2; }
        }
    }
}

// ================= K14: final combine over A0  (256 blocks) =================
__global__ void __launch_bounds__(256) k_final(Params P) {
    int t = blockIdx.x * 256 + threadIdx.x;
    int node = t >> 2, r = t & 3;
    if (node >= N0 || r >= 3) return;
    float* ws = P.ws;
    const int* rp = (int*)(ws + O_RP);
    const int* ei = (int*)(ws + O_EIDX);
    const float* yg = ws + O_YG3;
    const float* yl = ws + O_YL3;
    int r0 = rp[node], r1 = rp[node + 1];
    float ag = yg[node * 3 + r], al = yl[node * 3 + r];
    int e = r0;
    for (; e + 4 <= r1; e += 4) {
        int s0 = ei[e], s1 = ei[e + 1], s2 = ei[e + 2], s3 = ei[e + 3];
        ag += yg[s0 * 3 + r] + yg[s1 * 3 + r] + yg[s2 * 3 + r] + yg[s3 * 3 + r];
        al += yl[s0 * 3 + r] + yl[s1 * 3 + r] + yl[s2 * 3 + r] + yl[s3 * 3 + r];
    }
    for (; e < r1; e++) { ag += yg[ei[e] * 3 + r]; al += yl[ei[e] * 3 + r]; }
    float inv = 1.f / (float)(r1 - r0 + 1);
    P.out[node * 3 + r] = 0.01f * (ag * inv + P.bg3[r]) + 0.99f * (al * inv + P.bl3[r]);
}

extern "C" void kernel_launch(void* const* d_in, const int* in_sizes, int n_in,
                              void* d_out, int out_size, void* d_ws, size_t ws_size,
                              hipStream_t stream) {
    Params p;
    p.z     = (const float*)d_in[0];
    p.lin_w = (const float*)d_in[1];
    p.lin_b = (const float*)d_in[2];
    p.loc_w = (const float*)d_in[3];
    p.loc_b = (const float*)d_in[4];
    p.Wg    = (const float*)d_in[5];
    p.bg    = (const float*)d_in[8];
    p.Wg3   = (const float*)d_in[9];
    p.bg3   = (const float*)d_in[12];
    p.Wl    = (const float*)d_in[13];
    p.bl    = (const float*)d_in[16];
    p.Wl3   = (const float*)d_in[17];
    p.bl3   = (const float*)d_in[20];
    p.gam_g = (const float*)d_in[21];
    p.bet_g = (const float*)d_in[22];
    p.gam_l = (const float*)d_in[23];
    p.bet_l = (const float*)d_in[24];
    p.U0    = (const float*)d_in[25];
    p.U1    = (const float*)d_in[26];
    p.U2    = (const float*)d_in[27];
    p.U3    = (const float*)d_in[28];
    p.A0    = (const int*)d_in[29];
    p.A1    = (const int*)d_in[30];
    p.A2    = (const int*)d_in[31];
    p.A3    = (const int*)d_in[32];
    p.ws    = (float*)d_ws;
    p.out   = (float*)d_out;

    k_pre   <<<65,  256, 0, stream>>>(p);
    k_l2    <<<256, 256, 0, stream>>>(p);  // matvec 0:191 | hist | U3 gemm
    k_l3    <<<256, 256, 0, stream>>>(p);  // matvec 191:443 | scan
    k_l4    <<<133, 256, 0, stream>>>(p);  // matvec 443:512 | fill
    k_l5    <<<256, 512, 0, stream>>>(p);  // gather_l0 | gather_g0
    k_l6    <<<33,  512, 0, stream>>>(p);  // bnxw_l0 | bnxw_g0
    k_l7    <<<256, 512, 0, stream>>>(p);  // gather_l1 | gemm_g1
    k_l8    <<<48,  512, 0, stream>>>(p);  // bnxw_l1 | gather_g1
    k_l9    <<<242, 512, 0, stream>>>(p);  // gather_l2 | bnxw_g1
    k_l10   <<<96,  512, 0, stream>>>(p);  // bnxw_l2 | gemm_g2
    k_l11   <<<64,  512, 0, stream>>>(p);  // gather_g2
    k_l12   <<<8,   512, 0, stream>>>(p);  // bnxw_g2
    k_gemmU3<<<256, 256, 0, stream>>>(p);  // U0 @ xw3
    k_final <<<256, 256, 0, stream>>>(p);  // combine
}